// Round 6
// baseline (343.593 us; speedup 1.0000x reference)
//
#include <hip/hip_runtime.h>
#include <stdint.h>

// ---------- types ----------
using s8v  = __attribute__((ext_vector_type(8))) short;    // 8 bf16 (A/B frag)
using f4   = __attribute__((ext_vector_type(4))) float;    // C/D frag
using u32x4 = __attribute__((ext_vector_type(4))) uint32_t;
using u32x2 = __attribute__((ext_vector_type(2))) uint32_t;
using vf4  = __attribute__((ext_vector_type(4))) float;
using i4v  = __attribute__((ext_vector_type(4))) int;

typedef unsigned short ushortT;

// bf16 round-to-nearest-even
static __device__ __forceinline__ uint32_t bfr16(float f) {
  union { float f; uint32_t u; } v; v.f = f;
  return (v.u + 0x7FFFu + ((v.u >> 16) & 1u)) >> 16;
}
static __device__ __forceinline__ uint32_t pk2(float lo, float hi) {
  return (bfr16(hi) << 16) | (bfr16(lo) & 0xFFFFu);
}
// hardware packed f32x2 -> bf16x2 (RNE)
static __device__ __forceinline__ uint32_t cvtpk(float lo, float hi) {
  uint32_t r;
  asm("v_cvt_pk_bf16_f32 %0, %1, %2" : "=v"(r) : "v"(lo), "v"(hi));
  return r;
}
// async global->LDS, 16B per lane
static __device__ __forceinline__ void gl16(const void* g, void* l) {
  __builtin_amdgcn_global_load_lds((const __attribute__((address_space(1))) uint32_t*)g,
                                   (__attribute__((address_space(3))) uint32_t*)l, 16, 0, 0);
}

#define MFMA_BF16(A, B, C) __builtin_amdgcn_mfma_f32_16x16x32_bf16((A), (B), (C), 0, 0, 0)

// ---------------------------------------------------------------------------
// Kernel 0: weights -> bf16, transposed: Wt[640][512]
// ---------------------------------------------------------------------------
__global__ __launch_bounds__(64) void kprep(const float* __restrict__ Wg,
                                            const float* __restrict__ Wf,
                                            const float* __restrict__ Wh,
                                            ushortT* __restrict__ Wt) {
  const int cIdx = blockIdx.x;     // 0..639
  const int t = threadIdx.x;       // 64
  const float* src; int co, ldc;
  if (cIdx < 64)       { src = Wg; co = cIdx;       ldc = 64;  }
  else if (cIdx < 128) { src = Wf; co = cIdx - 64;  ldc = 64;  }
  else                 { src = Wh; co = cIdx - 128; ldc = 512; }
#pragma unroll
  for (int kk = 0; kk < 8; ++kk) {
    int k = kk * 64 + t;
    Wt[(size_t)cIdx * 512 + k] = (ushortT)bfr16(src[(size_t)k * ldc + co]);
  }
}

// ---------------------------------------------------------------------------
// Kernel 1: projection GEMM.  col-tile 0 -> Q [32768][64]; 1 -> K [32768][64];
// 2..9 -> Vt2 TILED: Vt2[b][kvtile=128][col=512][kv=32].
// ---------------------------------------------------------------------------
__global__ __launch_bounds__(256) void kproj(const float* __restrict__ x,
                                             const ushortT* __restrict__ Wt,
                                             const float* __restrict__ bg,
                                             const float* __restrict__ bfv,
                                             const float* __restrict__ bh,
                                             ushortT* __restrict__ Q,
                                             ushortT* __restrict__ K,
                                             ushortT* __restrict__ Vt) {
  __shared__ ushortT Al[64 * 64];
  __shared__ ushortT Bl[64 * 64];

  const int tid = threadIdx.x;
  const int w = tid >> 6, l = tid & 63, h = l >> 4, c = l & 15;
  const int ct = blockIdx.x, rt = blockIdx.y;
  const int row0 = rt * 64;

  f4 acc[4];
#pragma unroll
  for (int j = 0; j < 4; ++j) acc[j] = (f4){0.f, 0.f, 0.f, 0.f};

  const int arow = tid >> 2, aseg = tid & 3;
  const float* xrow = x + (size_t)(row0 + arow) * 512 + aseg * 16;

  for (int kk = 0; kk < 8; ++kk) {
    const int k0 = kk * 64;
    vf4 f0 = *(const vf4*)(xrow + k0 + 0);
    vf4 f1 = *(const vf4*)(xrow + k0 + 4);
    vf4 f2 = *(const vf4*)(xrow + k0 + 8);
    vf4 f3 = *(const vf4*)(xrow + k0 + 12);
    u32x4 ch0 = { pk2(f0[0], f0[1]), pk2(f0[2], f0[3]), pk2(f1[0], f1[1]), pk2(f1[2], f1[3]) };
    u32x4 ch1 = { pk2(f2[0], f2[1]), pk2(f2[2], f2[3]), pk2(f3[0], f3[1]), pk2(f3[2], f3[3]) };
    const int sw = arow & 7;
    *(u32x4*)((char*)Al + arow * 128 + (((aseg * 2 + 0) ^ sw) * 16)) = ch0;
    *(u32x4*)((char*)Al + arow * 128 + (((aseg * 2 + 1) ^ sw) * 16)) = ch1;
#pragma unroll
    for (int j = 0; j < 2; ++j) {
      const int col = w * 16 + j * 8 + (l >> 3);
      const int c7 = l & 7;
      const ushortT* src = Wt + (size_t)(ct * 64 + col) * 512 + k0 + 8 * (c7 ^ (l >> 3));
      gl16(src, (char*)Bl + (w * 128 + j * 64) * 16);
    }
    __syncthreads();
#pragma unroll
    for (int ks = 0; ks < 2; ++ks) {
      s8v af = *(const s8v*)((char*)Al + (w * 16 + c) * 128 + (((ks * 4 + h) ^ (c & 7)) * 16));
#pragma unroll
      for (int cj = 0; cj < 4; ++cj) {
        s8v bf8 = *(const s8v*)((char*)Bl + (cj * 16 + c) * 128 + (((ks * 4 + h) ^ (c & 7)) * 16));
        acc[cj] = MFMA_BF16(af, bf8, acc[cj]);
      }
    }
    __syncthreads();
  }

  const int colbase = ct * 64;
  const float* bias = (ct == 0) ? bg : (ct == 1) ? bfv : bh;
  const int bo = (ct < 2) ? 0 : (colbase - 128);
  const int rbase = row0 + w * 16 + h * 4;
  if (ct < 2) {
    ushortT* dst = (ct == 0) ? Q : K;
#pragma unroll
    for (int cj = 0; cj < 4; ++cj) {
      const int cl = cj * 16 + c;
      const float bv = bias[cl];
#pragma unroll
      for (int r = 0; r < 4; ++r)
        dst[(size_t)(rbase + r) * 64 + cl] = (ushortT)bfr16(acc[cj][r] + bv);
    }
  } else {
    const int b = row0 >> 12;
    const int n0 = (row0 & 4095) + w * 16 + h * 4;
    const int tt = n0 >> 5, kvo = n0 & 31;
#pragma unroll
    for (int cj = 0; cj < 4; ++cj) {
      const int cl = cj * 16 + c;
      const float bv = bias[bo + cl];
      const int vcol = bo + cl;
      u32x2 dd = { pk2(acc[cj][0] + bv, acc[cj][1] + bv),
                   pk2(acc[cj][2] + bv, acc[cj][3] + bv) };
      *(u32x2*)(Vt + (((size_t)(b * 128 + tt) * 512 + vcol) * 32 + kvo)) = dd;
    }
  }
}

// ---------------------------------------------------------------------------
// Kernel 2: flash attention, KVBLK=64, alternating producer groups.
// Waves 0-3 produce P for EVEN tiles, waves 4-7 for ODD tiles, 2 tiles ahead
// (produce(t+2) at iter t) -> each SIMD has 2 producers + 2 pure-PV waves
// every iter; produce tail overlaps other waves' PV instead of gating the
// barrier.  Shared running-max m in LDS (serial across tiles, 1-iter slack);
// P/alpha/flag 4-deep; K tiles 3-deep LDS rotation (gl16-staged).
// __launch_bounds__(512,4): 2 blocks/CU requires arch VGPR <= 64.
// ---------------------------------------------------------------------------
__global__ __launch_bounds__(512, 4) void kattn(const ushortT* __restrict__ Qg,
                                                const ushortT* __restrict__ Kg,
                                                const ushortT* __restrict__ Vt2,
                                                const float* __restrict__ x,
                                                const float* __restrict__ gamma,
                                                float* __restrict__ out) {
  __shared__ __align__(16) uint32_t Pl[4][2][1024];   // 32KB [slot][kvgrp][..]
  __shared__ __align__(16) ushortT Klds[3][64 * 64];  // 24KB K tiles, 3-rot
  __shared__ __align__(16) float alpha_s[4][64];      // 1KB
  __shared__ __align__(16) float m_s[64];             // shared running max
  __shared__ __align__(16) int   flag_s[4][4];
  __shared__ __align__(16) float lsum_s[2][64];

  const int tid = threadIdx.x;
  const int w = tid >> 6, l = tid & 63, h = l >> 4, c = l & 15;
  const int myq = w & 3;                               // q-block this wave produces
  const int bb = blockIdx.x & 7, qb = blockIdx.x >> 3; // XCD-aware swizzle
  const size_t qrow0 = (size_t)bb * 4096 + (size_t)qb * 64;

  f4 acc[4][4];
#pragma unroll
  for (int qi = 0; qi < 4; ++qi)
#pragma unroll
    for (int vj = 0; vj < 4; ++vj) acc[qi][vj] = (f4){0.f, 0.f, 0.f, 0.f};

  const ushortT* Kb = Kg + (size_t)bb * 4096 * 64;
  const ushortT* Vb = Vt2 + (size_t)bb * 512 * 4096;

  // V source: wave w owns cols w*64..w*64+63; +32768 elems per 64-kv tile
  const ushortT* vptr = Vb + (size_t)(w * 64 + c) * 32 + h * 8;
  // K staging source offset (pre-swizzled; 8-wave split, 1KB per wave)
  const size_t koff8 = (size_t)(w * 8 + (l >> 3)) * 64 + 8 * ((l & 7) ^ (l >> 3));

  // Q fragments (B-operand of S^T): q = myq*16 + c  (all 8 waves)
  s8v qf[2];
#pragma unroll
  for (int ks = 0; ks < 2; ++ks)
    qf[ks] = *(const s8v*)(Qg + (qrow0 + myq * 16 + c) * 64 + ks * 32 + h * 8);

  float l_run = 0.0f;        // per-lane partial for this wave's own tiles
  float ts_pending = 0.0f;   // tile-sum produced 2 iters ago, consumed at its iter

  // softmax tail: sc[4] = S^T fragments (lane c = q; kv = j*16 + h*4 + r)
  auto sm_tail = [&](const f4* sc, int nb, float mprev) {
    float tm = fmaxf(fmaxf(fmaxf(sc[0][0], sc[0][1]), fmaxf(sc[0][2], sc[0][3])),
                     fmaxf(fmaxf(sc[1][0], sc[1][1]), fmaxf(sc[1][2], sc[1][3])));
    tm = fmaxf(tm, fmaxf(fmaxf(fmaxf(sc[2][0], sc[2][1]), fmaxf(sc[2][2], sc[2][3])),
                         fmaxf(fmaxf(sc[3][0], sc[3][1]), fmaxf(sc[3][2], sc[3][3]))));
    const unsigned long long bal = __ballot(tm > mprev + 8.0f);
    float mcur = mprev;
    if (bal) {
      tm = fmaxf(tm, __shfl_xor(tm, 16));
      tm = fmaxf(tm, __shfl_xor(tm, 32));
      mcur = fmaxf(mprev, tm);
      const float al = __expf(mprev - mcur);   // 0 on first tile
      if (h == 0) {
        m_s[myq * 16 + c] = mcur;
        alpha_s[nb][myq * 16 + c] = al;
      }
    }
    if (l == 0) flag_s[nb][myq] = bal ? 1 : 0;
    float ps = 0.0f;
#pragma unroll
    for (int j = 0; j < 4; ++j) {
      const float p0 = __expf(sc[j][0] - mcur), p1 = __expf(sc[j][1] - mcur);
      const float p2 = __expf(sc[j][2] - mcur), p3 = __expf(sc[j][3] - mcur);
      ps += (p0 + p1) + (p2 + p3);
      const int g = j >> 1, kj = j & 1;
      const int lane0 = (myq * 64 + c + 16 * (kj * 2 + (h >> 1))) * 4 + (h & 1) * 2;
      Pl[nb][g][lane0 + 0] = cvtpk(p0, p1);
      Pl[nb][g][lane0 + 1] = cvtpk(p2, p3);
    }
    ts_pending = ps;
  };

  // ---- prologue: group A produces tile 0 (m = -inf); stage K(2) -> Klds[2];
  //      barrier; group B produces tile 1 (m from LDS); barrier.
  if (w < 4) {
    f4 sc[4];
#pragma unroll
    for (int j = 0; j < 4; ++j) sc[j] = (f4){0.f, 0.f, 0.f, 0.f};
    __builtin_amdgcn_s_setprio(1);
#pragma unroll
    for (int j = 0; j < 4; ++j)
#pragma unroll
      for (int ks = 0; ks < 2; ++ks) {
        s8v kf = *(const s8v*)(Kb + (size_t)(j * 16 + c) * 64 + ks * 32 + h * 8);
        sc[j] = MFMA_BF16(kf, qf[ks], sc[j]);
      }
    __builtin_amdgcn_s_setprio(0);
    sm_tail(sc, 0, -__builtin_inff());
  }
  gl16(Kb + 2 * 4096 + koff8, (char*)Klds[2] + w * 1024);
  asm volatile("s_waitcnt vmcnt(0) lgkmcnt(0)" ::: "memory");
  __builtin_amdgcn_s_barrier();
  if (w >= 4) {
    const float mprev = m_s[myq * 16 + c];
    f4 sc[4];
#pragma unroll
    for (int j = 0; j < 4; ++j) sc[j] = (f4){0.f, 0.f, 0.f, 0.f};
    __builtin_amdgcn_s_setprio(1);
#pragma unroll
    for (int j = 0; j < 4; ++j)
#pragma unroll
      for (int ks = 0; ks < 2; ++ks) {
        s8v kf = *(const s8v*)(Kb + 4096 + (size_t)(j * 16 + c) * 64 + ks * 32 + h * 8);
        sc[j] = MFMA_BF16(kf, qf[ks], sc[j]);
      }
    __builtin_amdgcn_s_setprio(0);
    sm_tail(sc, 1, mprev);
  }
  asm volatile("s_waitcnt vmcnt(0) lgkmcnt(0)" ::: "memory");
  __builtin_amdgcn_s_barrier();

  int kb3 = 2, wb3 = 0;   // Klds read / write rotation
  for (int t = 0; t < 64; ++t) {
    const int cur = t & 3;
    // ---- stage K(t+3) -> Klds[wb3] (1KB per wave; in flight through iter)
    if (t < 61)
      gl16(Kb + (size_t)(t + 3) * 4096 + koff8, (char*)Klds[wb3] + w * 1024);
    // ---- P fragments + flags for tile t
    s8v pa0[4], pa1[4];
#pragma unroll
    for (int qi = 0; qi < 4; ++qi) {
      pa0[qi] = *(const s8v*)&Pl[cur][0][(qi * 64 + l) * 4];
      pa1[qi] = *(const s8v*)&Pl[cur][1][(qi * 64 + l) * 4];
    }
    i4v fl = *(const i4v*)&flag_s[cur][0];
    // ---- l partial update (consume tile t; scalar LDS reads, no dyn vec idx)
    {
      const int flv = flag_s[cur][myq];
      const float av = flv ? alpha_s[cur][myq * 16 + c] : 1.0f;
      l_run = l_run * av + (((w >> 2) == (t & 1)) ? ts_pending : 0.0f);
    }
    // ---- deferred acc rescale
#pragma unroll
    for (int qi = 0; qi < 4; ++qi) {
      if (fl[qi]) {
        f4 a4 = *(const f4*)&alpha_s[cur][qi * 16 + h * 4];
#pragma unroll
        for (int vj = 0; vj < 4; ++vj)
#pragma unroll
          for (int r = 0; r < 4; ++r) acc[qi][vj][r] *= a4[r];
      }
    }
    // ---- PV: 4 quarters, each {2 V-loads, 8 MFMA}
#pragma unroll
    for (int vj = 0; vj < 4; ++vj) {
      s8v vf0 = *(const s8v*)(vptr + vj * 512);
      s8v vf1 = *(const s8v*)(vptr + 16384 + vj * 512);
      __builtin_amdgcn_s_setprio(1);
#pragma unroll
      for (int qi = 0; qi < 4; ++qi) {
        acc[qi][vj] = MFMA_BF16(pa0[qi], vf0, acc[qi][vj]);
        acc[qi][vj] = MFMA_BF16(pa1[qi], vf1, acc[qi][vj]);
      }
      __builtin_amdgcn_s_setprio(0);
    }
    vptr += 32768;
    // ---- produce tile t+2 (group (t+2)&1 == t&1), K from Klds[kb3]
    if (t < 62 && (w >> 2) == (t & 1)) {
      const float mprev = m_s[myq * 16 + c];
      const char* kbp = (const char*)Klds[kb3];
      f4 sc[4];
#pragma unroll
      for (int j = 0; j < 4; ++j) sc[j] = (f4){0.f, 0.f, 0.f, 0.f};
      __builtin_amdgcn_s_setprio(1);
#pragma unroll
      for (int j = 0; j < 4; ++j)
#pragma unroll
        for (int ks = 0; ks < 2; ++ks) {
          s8v kf = *(const s8v*)(kbp + (size_t)(j * 16 + c) * 128 +
                                 (((ks * 4 + h) ^ (c & 7)) * 16));
          sc[j] = MFMA_BF16(kf, qf[ks], sc[j]);
        }
      __builtin_amdgcn_s_setprio(0);
      sm_tail(sc, (t + 2) & 3, mprev);
    }
    kb3 = (kb3 == 2) ? 0 : kb3 + 1;
    wb3 = (wb3 == 2) ? 0 : wb3 + 1;
    if (t < 63) {
      asm volatile("s_waitcnt vmcnt(0) lgkmcnt(0)" ::: "memory");
      __builtin_amdgcn_s_barrier();
    }
  }

  // ---- finalize: combine per-lane l partials (h groups, then even/odd groups)
  l_run += __shfl_xor(l_run, 16);
  l_run += __shfl_xor(l_run, 32);
  if (h == 0) lsum_s[w >> 2][myq * 16 + c] = l_run;
  __syncthreads();
#pragma unroll
  for (int qi = 0; qi < 4; ++qi) {
    f4 lA = *(const f4*)(&lsum_s[0][qi * 16 + h * 4]);
    f4 lB = *(const f4*)(&lsum_s[1][qi * 16 + h * 4]);
    f4 rl;
#pragma unroll
    for (int r = 0; r < 4; ++r) rl[r] = 1.0f / (lA[r] + lB[r]);
#pragma unroll
    for (int vj = 0; vj < 4; ++vj) {
      const int colg = w * 64 + vj * 16 + c;
      const float gm = gamma[colg];
#pragma unroll
      for (int r = 0; r < 4; ++r) {
        const size_t idx = (qrow0 + qi * 16 + h * 4 + r) * 512 + colg;
        out[idx] = gm * (acc[qi][vj][r] * rl[r]) + x[idx];
      }
    }
  }
}

// ---------------------------------------------------------------------------
extern "C" void kernel_launch(void* const* d_in, const int* in_sizes, int n_in,
                              void* d_out, int out_size, void* d_ws, size_t ws_size,
                              hipStream_t stream) {
  const float* x     = (const float*)d_in[0];
  const float* Wg    = (const float*)d_in[1];
  const float* bg    = (const float*)d_in[2];
  const float* Wf    = (const float*)d_in[3];
  const float* bfv   = (const float*)d_in[4];
  const float* Wh    = (const float*)d_in[5];
  const float* bh    = (const float*)d_in[6];
  const float* gamma = (const float*)d_in[7];
  float* out = (float*)d_out;
  char* ws = (char*)d_ws;

  ushortT* Q  = (ushortT*)(ws);
  ushortT* K  = (ushortT*)(ws + ((size_t)4 << 20));
  ushortT* Vt = (ushortT*)(ws + ((size_t)8 << 20));
  ushortT* Wt = (ushortT*)(ws + ((size_t)40 << 20));

  kprep<<<dim3(640), dim3(64), 0, stream>>>(Wg, Wf, Wh, Wt);
  kproj<<<dim3(10, 512), dim3(256), 0, stream>>>(x, Wt, bg, bfv, bh, Q, K, Vt);
  kattn<<<dim3(512), dim3(512), 0, stream>>>(Q, K, Vt, x, gamma, out);
}

// Round 7
// 337.657 us; speedup vs baseline: 1.0176x; 1.0176x over previous
//
#include <hip/hip_runtime.h>
#include <stdint.h>

// ---------- types ----------
using s8v  = __attribute__((ext_vector_type(8))) short;    // 8 bf16 (A/B frag)
using f4   = __attribute__((ext_vector_type(4))) float;    // C/D frag
using u32x4 = __attribute__((ext_vector_type(4))) uint32_t;
using u32x2 = __attribute__((ext_vector_type(2))) uint32_t;
using vf4  = __attribute__((ext_vector_type(4))) float;
using i4v  = __attribute__((ext_vector_type(4))) int;

typedef unsigned short ushortT;

// bf16 round-to-nearest-even
static __device__ __forceinline__ uint32_t bfr16(float f) {
  union { float f; uint32_t u; } v; v.f = f;
  return (v.u + 0x7FFFu + ((v.u >> 16) & 1u)) >> 16;
}
static __device__ __forceinline__ uint32_t pk2(float lo, float hi) {
  return (bfr16(hi) << 16) | (bfr16(lo) & 0xFFFFu);
}
// hardware packed f32x2 -> bf16x2 (RNE)
static __device__ __forceinline__ uint32_t cvtpk(float lo, float hi) {
  uint32_t r;
  asm("v_cvt_pk_bf16_f32 %0, %1, %2" : "=v"(r) : "v"(lo), "v"(hi));
  return r;
}
// async global->LDS, 16B per lane
static __device__ __forceinline__ void gl16(const void* g, void* l) {
  __builtin_amdgcn_global_load_lds((const __attribute__((address_space(1))) uint32_t*)g,
                                   (__attribute__((address_space(3))) uint32_t*)l, 16, 0, 0);
}

#define MFMA_BF16(A, B, C) __builtin_amdgcn_mfma_f32_16x16x32_bf16((A), (B), (C), 0, 0, 0)

// ---------------------------------------------------------------------------
// Kernel 0: weights -> bf16, transposed: Wt[640][512]
// ---------------------------------------------------------------------------
__global__ __launch_bounds__(64) void kprep(const float* __restrict__ Wg,
                                            const float* __restrict__ Wf,
                                            const float* __restrict__ Wh,
                                            ushortT* __restrict__ Wt) {
  const int cIdx = blockIdx.x;     // 0..639
  const int t = threadIdx.x;       // 64
  const float* src; int co, ldc;
  if (cIdx < 64)       { src = Wg; co = cIdx;       ldc = 64;  }
  else if (cIdx < 128) { src = Wf; co = cIdx - 64;  ldc = 64;  }
  else                 { src = Wh; co = cIdx - 128; ldc = 512; }
#pragma unroll
  for (int kk = 0; kk < 8; ++kk) {
    int k = kk * 64 + t;
    Wt[(size_t)cIdx * 512 + k] = (ushortT)bfr16(src[(size_t)k * ldc + co]);
  }
}

// ---------------------------------------------------------------------------
// Kernel 1: projection GEMM.  col-tile 0 -> Q [32768][64]; 1 -> K [32768][64];
// 2..9 -> Vt2 TILED: Vt2[b][kvtile=128][col=512][kv=32].
// ---------------------------------------------------------------------------
__global__ __launch_bounds__(256) void kproj(const float* __restrict__ x,
                                             const ushortT* __restrict__ Wt,
                                             const float* __restrict__ bg,
                                             const float* __restrict__ bfv,
                                             const float* __restrict__ bh,
                                             ushortT* __restrict__ Q,
                                             ushortT* __restrict__ K,
                                             ushortT* __restrict__ Vt) {
  __shared__ ushortT Al[64 * 64];
  __shared__ ushortT Bl[64 * 64];

  const int tid = threadIdx.x;
  const int w = tid >> 6, l = tid & 63, h = l >> 4, c = l & 15;
  const int ct = blockIdx.x, rt = blockIdx.y;
  const int row0 = rt * 64;

  f4 acc[4];
#pragma unroll
  for (int j = 0; j < 4; ++j) acc[j] = (f4){0.f, 0.f, 0.f, 0.f};

  const int arow = tid >> 2, aseg = tid & 3;
  const float* xrow = x + (size_t)(row0 + arow) * 512 + aseg * 16;

  for (int kk = 0; kk < 8; ++kk) {
    const int k0 = kk * 64;
    vf4 f0 = *(const vf4*)(xrow + k0 + 0);
    vf4 f1 = *(const vf4*)(xrow + k0 + 4);
    vf4 f2 = *(const vf4*)(xrow + k0 + 8);
    vf4 f3 = *(const vf4*)(xrow + k0 + 12);
    u32x4 ch0 = { pk2(f0[0], f0[1]), pk2(f0[2], f0[3]), pk2(f1[0], f1[1]), pk2(f1[2], f1[3]) };
    u32x4 ch1 = { pk2(f2[0], f2[1]), pk2(f2[2], f2[3]), pk2(f3[0], f3[1]), pk2(f3[2], f3[3]) };
    const int sw = arow & 7;
    *(u32x4*)((char*)Al + arow * 128 + (((aseg * 2 + 0) ^ sw) * 16)) = ch0;
    *(u32x4*)((char*)Al + arow * 128 + (((aseg * 2 + 1) ^ sw) * 16)) = ch1;
#pragma unroll
    for (int j = 0; j < 2; ++j) {
      const int col = w * 16 + j * 8 + (l >> 3);
      const int c7 = l & 7;
      const ushortT* src = Wt + (size_t)(ct * 64 + col) * 512 + k0 + 8 * (c7 ^ (l >> 3));
      gl16(src, (char*)Bl + (w * 128 + j * 64) * 16);
    }
    __syncthreads();
#pragma unroll
    for (int ks = 0; ks < 2; ++ks) {
      s8v af = *(const s8v*)((char*)Al + (w * 16 + c) * 128 + (((ks * 4 + h) ^ (c & 7)) * 16));
#pragma unroll
      for (int cj = 0; cj < 4; ++cj) {
        s8v bf8 = *(const s8v*)((char*)Bl + (cj * 16 + c) * 128 + (((ks * 4 + h) ^ (c & 7)) * 16));
        acc[cj] = MFMA_BF16(af, bf8, acc[cj]);
      }
    }
    __syncthreads();
  }

  const int colbase = ct * 64;
  const float* bias = (ct == 0) ? bg : (ct == 1) ? bfv : bh;
  const int bo = (ct < 2) ? 0 : (colbase - 128);
  const int rbase = row0 + w * 16 + h * 4;
  if (ct < 2) {
    ushortT* dst = (ct == 0) ? Q : K;
#pragma unroll
    for (int cj = 0; cj < 4; ++cj) {
      const int cl = cj * 16 + c;
      const float bv = bias[cl];
#pragma unroll
      for (int r = 0; r < 4; ++r)
        dst[(size_t)(rbase + r) * 64 + cl] = (ushortT)bfr16(acc[cj][r] + bv);
    }
  } else {
    const int b = row0 >> 12;
    const int n0 = (row0 & 4095) + w * 16 + h * 4;
    const int tt = n0 >> 5, kvo = n0 & 31;
#pragma unroll
    for (int cj = 0; cj < 4; ++cj) {
      const int cl = cj * 16 + c;
      const float bv = bias[bo + cl];
      const int vcol = bo + cl;
      u32x2 dd = { pk2(acc[cj][0] + bv, acc[cj][1] + bv),
                   pk2(acc[cj][2] + bv, acc[cj][3] + bv) };
      *(u32x2*)(Vt + (((size_t)(b * 128 + tt) * 512 + vcol) * 32 + kvo)) = dd;
    }
  }
}

// ---------------------------------------------------------------------------
// Kernel 2: flash attention, M=128 q-rows per block (1024 threads, 16 waves),
// KVBLK=64.  Same V tile feeds 2x the q-rows -> V bytes/MFMA halved; wave
// pairs (w, w+8) read identical V addresses (L1 reuse).
// Waves 0-7: producers (q-block w, every tile, R5 discipline, m in regs).
// Waves 8-15: K-tile stagers (gl16, 2-deep rotation).
// All 16: PV over (q-half w>>3, 64 cols w&7).
// grid = 256 (bb = blk&7 XCD-local batch, qs = blk>>3), 1 block/CU.
// ---------------------------------------------------------------------------
__global__ __launch_bounds__(1024, 4) void kattn(const ushortT* __restrict__ Qg,
                                                 const ushortT* __restrict__ Kg,
                                                 const ushortT* __restrict__ Vt2,
                                                 const float* __restrict__ x,
                                                 const float* __restrict__ gamma,
                                                 float* __restrict__ out) {
  __shared__ __align__(16) uint32_t Pl[2][2][2048];   // 32KB [slot][kvgrp][q8*64*4]
  __shared__ __align__(16) ushortT Klds[2][64 * 64];  // 16KB K tiles, dbuf
  __shared__ __align__(16) float alpha_s[2][128];     // 1KB
  __shared__ __align__(16) int   flag_s[2][8];
  __shared__ __align__(16) float lsum_s[128];

  const int tid = threadIdx.x;
  const int w = tid >> 6, l = tid & 63, h = l >> 4, c = l & 15;
  const int hw = w >> 3;          // q-half for PV
  const int wc = w & 7;           // col group (64 cols)
  const int myq = w & 7;          // producer q-block (waves 0-7)
  const int bb = blockIdx.x & 7, qs = blockIdx.x >> 3;   // XCD-aware swizzle
  const size_t qrow0 = (size_t)bb * 4096 + (size_t)qs * 128;

  f4 acc[4][4];
#pragma unroll
  for (int qi = 0; qi < 4; ++qi)
#pragma unroll
    for (int vj = 0; vj < 4; ++vj) acc[qi][vj] = (f4){0.f, 0.f, 0.f, 0.f};

  const ushortT* Kb = Kg + (size_t)bb * 4096 * 64;
  const ushortT* Vb = Vt2 + (size_t)bb * 512 * 4096;

  // V source: wave pair (w, w+8) -> identical addresses (L1 reuse)
  const ushortT* vptr = Vb + (size_t)(wc * 64 + c) * 32 + h * 8;  // +32768/iter
  // K staging source offset for stager waves (pre-swizzled)
  const int sw8 = w & 7;
  const size_t koff8 = (size_t)(sw8 * 8 + (l >> 3)) * 64 + 8 * ((l & 7) ^ (l >> 3));

  // Q fragments (producers only): q = myq*16 + c
  s8v qf[2];
  if (w < 8) {
#pragma unroll
    for (int ks = 0; ks < 2; ++ks)
      qf[ks] = *(const s8v*)(Qg + (qrow0 + myq * 16 + c) * 64 + ks * 32 + h * 8);
  }
  float m_run = -__builtin_inff();
  float l_run = 0.0f;   // per-lane partial; combined across h at epilogue

  // softmax tail: sc[4] = S^T fragments (lane c = q; kv = j*16 + h*4 + r)
  auto softmax_store = [&](const f4* sc, int nb) {
    float tm = fmaxf(fmaxf(fmaxf(sc[0][0], sc[0][1]), fmaxf(sc[0][2], sc[0][3])),
                     fmaxf(fmaxf(sc[1][0], sc[1][1]), fmaxf(sc[1][2], sc[1][3])));
    tm = fmaxf(tm, fmaxf(fmaxf(fmaxf(sc[2][0], sc[2][1]), fmaxf(sc[2][2], sc[2][3])),
                         fmaxf(fmaxf(sc[3][0], sc[3][1]), fmaxf(sc[3][2], sc[3][3]))));
    // ballot-first defer-max: cross-lane reduce only when threshold trips
    const unsigned long long bal = __ballot(tm > m_run + 8.0f);
    float al = 1.0f;
    if (bal) {
      tm = fmaxf(tm, __shfl_xor(tm, 16));
      tm = fmaxf(tm, __shfl_xor(tm, 32));
      const float mn = fmaxf(m_run, tm);
      al = __expf(m_run - mn);   // 0 on first tile
      m_run = mn;
    }
    float ps = 0.0f;
#pragma unroll
    for (int j = 0; j < 4; ++j) {
      const float p0 = __expf(sc[j][0] - m_run), p1 = __expf(sc[j][1] - m_run);
      const float p2 = __expf(sc[j][2] - m_run), p3 = __expf(sc[j][3] - m_run);
      ps += (p0 + p1) + (p2 + p3);
      const int g = j >> 1, kj = j & 1;
      const int lane0 = (myq * 64 + c + 16 * (kj * 2 + (h >> 1))) * 4 + (h & 1) * 2;
      Pl[nb][g][lane0 + 0] = cvtpk(p0, p1);
      Pl[nb][g][lane0 + 1] = cvtpk(p2, p3);
    }
    l_run = l_run * al + ps;
    if (bal && h == 0) alpha_s[nb][myq * 16 + c] = al;
    if (l == 0) flag_s[nb][myq] = bal ? 1 : 0;
  };

  // ---- prologue: producers do tile 0 from global K; stagers stage K(1)
  if (w < 8) {
    f4 sc[4];
#pragma unroll
    for (int j = 0; j < 4; ++j) sc[j] = (f4){0.f, 0.f, 0.f, 0.f};
    __builtin_amdgcn_s_setprio(1);
#pragma unroll
    for (int j = 0; j < 4; ++j)
#pragma unroll
      for (int ks = 0; ks < 2; ++ks) {
        s8v kf = *(const s8v*)(Kb + (size_t)(j * 16 + c) * 64 + ks * 32 + h * 8);
        sc[j] = MFMA_BF16(kf, qf[ks], sc[j]);
      }
    __builtin_amdgcn_s_setprio(0);
    softmax_store(sc, 0);
  } else {
    gl16(Kb + 4096 + koff8, (char*)Klds[1] + sw8 * 1024);
  }
  asm volatile("s_waitcnt vmcnt(0) lgkmcnt(0)" ::: "memory");
  __builtin_amdgcn_s_barrier();

  for (int t = 0; t < 64; ++t) {
    const int cur = t & 1;
    // ---- stagers: K(t+2) -> Klds[t&1] (in flight through the iteration)
    if (w >= 8 && t < 62)
      gl16(Kb + (size_t)(t + 2) * 4096 + koff8, (char*)Klds[cur] + sw8 * 1024);
    // ---- P fragments + flags for tile t (own q-half)
    s8v pa0[4], pa1[4];
#pragma unroll
    for (int qi = 0; qi < 4; ++qi) {
      pa0[qi] = *(const s8v*)&Pl[cur][0][((hw * 4 + qi) * 64 + l) * 4];
      pa1[qi] = *(const s8v*)&Pl[cur][1][((hw * 4 + qi) * 64 + l) * 4];
    }
    i4v fl = *(const i4v*)&flag_s[cur][hw * 4];
    // ---- deferred acc rescale
#pragma unroll
    for (int qi = 0; qi < 4; ++qi) {
      if (fl[qi]) {
        f4 a4 = *(const f4*)&alpha_s[cur][(hw * 4 + qi) * 16 + h * 4];
#pragma unroll
        for (int vj = 0; vj < 4; ++vj)
#pragma unroll
          for (int r = 0; r < 4; ++r) acc[qi][vj][r] *= a4[r];
      }
    }
    // ---- PV: 4 quarters, each {2 V-loads, 8 MFMA}
#pragma unroll
    for (int vj = 0; vj < 4; ++vj) {
      s8v vf0 = *(const s8v*)(vptr + vj * 512);
      s8v vf1 = *(const s8v*)(vptr + 16384 + vj * 512);
      __builtin_amdgcn_s_setprio(1);
#pragma unroll
      for (int qi = 0; qi < 4; ++qi) {
        acc[qi][vj] = MFMA_BF16(pa0[qi], vf0, acc[qi][vj]);
        acc[qi][vj] = MFMA_BF16(pa1[qi], vf1, acc[qi][vj]);
      }
      __builtin_amdgcn_s_setprio(0);
    }
    vptr += 32768;
    // ---- producers: tile t+1 from Klds[(t+1)&1]
    if (t < 63 && w < 8) {
      const char* kbp = (const char*)Klds[cur ^ 1];
      f4 sc[4];
#pragma unroll
      for (int j = 0; j < 4; ++j) sc[j] = (f4){0.f, 0.f, 0.f, 0.f};
      __builtin_amdgcn_s_setprio(1);
#pragma unroll
      for (int j = 0; j < 4; ++j)
#pragma unroll
        for (int ks = 0; ks < 2; ++ks) {
          s8v kf = *(const s8v*)(kbp + (size_t)(j * 16 + c) * 128 +
                                 (((ks * 4 + h) ^ (c & 7)) * 16));
          sc[j] = MFMA_BF16(kf, qf[ks], sc[j]);
        }
      __builtin_amdgcn_s_setprio(0);
      softmax_store(sc, cur ^ 1);
    }
    if (t < 63) {
      asm volatile("s_waitcnt vmcnt(0) lgkmcnt(0)" ::: "memory");
      __builtin_amdgcn_s_barrier();
    }
  }

  // ---- finalize: combine per-lane l partials across h, then epilogue
  l_run += __shfl_xor(l_run, 16);
  l_run += __shfl_xor(l_run, 32);
  if (w < 8 && h == 0) lsum_s[myq * 16 + c] = l_run;
  __syncthreads();
#pragma unroll
  for (int qi = 0; qi < 4; ++qi) {
    f4 l4 = *(const f4*)(&lsum_s[(hw * 4 + qi) * 16 + h * 4]);
    f4 rl;
#pragma unroll
    for (int r = 0; r < 4; ++r) rl[r] = 1.0f / l4[r];
#pragma unroll
    for (int vj = 0; vj < 4; ++vj) {
      const int colg = wc * 64 + vj * 16 + c;
      const float gm = gamma[colg];
#pragma unroll
      for (int r = 0; r < 4; ++r) {
        const size_t idx = (qrow0 + hw * 64 + qi * 16 + h * 4 + r) * 512 + colg;
        out[idx] = gm * (acc[qi][vj][r] * rl[r]) + x[idx];
      }
    }
  }
}

// ---------------------------------------------------------------------------
extern "C" void kernel_launch(void* const* d_in, const int* in_sizes, int n_in,
                              void* d_out, int out_size, void* d_ws, size_t ws_size,
                              hipStream_t stream) {
  const float* x     = (const float*)d_in[0];
  const float* Wg    = (const float*)d_in[1];
  const float* bg    = (const float*)d_in[2];
  const float* Wf    = (const float*)d_in[3];
  const float* bfv   = (const float*)d_in[4];
  const float* Wh    = (const float*)d_in[5];
  const float* bh    = (const float*)d_in[6];
  const float* gamma = (const float*)d_in[7];
  float* out = (float*)d_out;
  char* ws = (char*)d_ws;

  ushortT* Q  = (ushortT*)(ws);
  ushortT* K  = (ushortT*)(ws + ((size_t)4 << 20));
  ushortT* Vt = (ushortT*)(ws + ((size_t)8 << 20));
  ushortT* Wt = (ushortT*)(ws + ((size_t)40 << 20));

  kprep<<<dim3(640), dim3(64), 0, stream>>>(Wg, Wf, Wh, Wt);
  kproj<<<dim3(10, 512), dim3(256), 0, stream>>>(x, Wt, bg, bfv, bh, Q, K, Vt);
  kattn<<<dim3(256), dim3(1024), 0, stream>>>(Q, K, Vt, x, gamma, out);
}

// Round 8
// 251.909 us; speedup vs baseline: 1.3640x; 1.3404x over previous
//
#include <hip/hip_runtime.h>
#include <stdint.h>

// ---------- types ----------
using s8v  = __attribute__((ext_vector_type(8))) short;    // 8 bf16 (A/B frag)
using f4   = __attribute__((ext_vector_type(4))) float;    // C/D frag
using u32x4 = __attribute__((ext_vector_type(4))) uint32_t;
using u32x2 = __attribute__((ext_vector_type(2))) uint32_t;
using vf4  = __attribute__((ext_vector_type(4))) float;
using i4v  = __attribute__((ext_vector_type(4))) int;

typedef unsigned short ushortT;

// bf16 round-to-nearest-even
static __device__ __forceinline__ uint32_t bfr16(float f) {
  union { float f; uint32_t u; } v; v.f = f;
  return (v.u + 0x7FFFu + ((v.u >> 16) & 1u)) >> 16;
}
static __device__ __forceinline__ uint32_t pk2(float lo, float hi) {
  return (bfr16(hi) << 16) | (bfr16(lo) & 0xFFFFu);
}
// pack 4 f32 -> 4 fp8 e4m3 bytes (saturating RNE)
static __device__ __forceinline__ uint32_t pk4fp8(float a, float b, float cc, float d) {
  int w = __builtin_amdgcn_cvt_pk_fp8_f32(a, b, 0, false);    // bytes 0,1
  w = __builtin_amdgcn_cvt_pk_fp8_f32(cc, d, w, true);        // bytes 2,3
  return (uint32_t)w;
}
// async global->LDS, 16B per lane
static __device__ __forceinline__ void gl16(const void* g, void* l) {
  __builtin_amdgcn_global_load_lds((const __attribute__((address_space(1))) uint32_t*)g,
                                   (__attribute__((address_space(3))) uint32_t*)l, 16, 0, 0);
}

#define MFMA_BF16(A, B, C) __builtin_amdgcn_mfma_f32_16x16x32_bf16((A), (B), (C), 0, 0, 0)
#define MFMA_FP8(A, B, C)  __builtin_amdgcn_mfma_f32_16x16x32_fp8_fp8((A), (B), (C), 0, 0, 0)

// ---------------------------------------------------------------------------
// Kernel 0: weights -> bf16, transposed: Wt[640][512]
// ---------------------------------------------------------------------------
__global__ __launch_bounds__(64) void kprep(const float* __restrict__ Wg,
                                            const float* __restrict__ Wf,
                                            const float* __restrict__ Wh,
                                            ushortT* __restrict__ Wt) {
  const int cIdx = blockIdx.x;     // 0..639
  const int t = threadIdx.x;       // 64
  const float* src; int co, ldc;
  if (cIdx < 64)       { src = Wg; co = cIdx;       ldc = 64;  }
  else if (cIdx < 128) { src = Wf; co = cIdx - 64;  ldc = 64;  }
  else                 { src = Wh; co = cIdx - 128; ldc = 512; }
#pragma unroll
  for (int kk = 0; kk < 8; ++kk) {
    int k = kk * 64 + t;
    Wt[(size_t)cIdx * 512 + k] = (ushortT)bfr16(src[(size_t)k * ldc + co]);
  }
}

// ---------------------------------------------------------------------------
// Kernel 1: projection GEMM.  col-tile 0 -> Q [32768][64]; 1 -> K [32768][64];
// 2..9 -> V8 TILED fp8 e4m3: V8[b][kvtile=128][col=512][kv=32] (1 B/elem).
// ---------------------------------------------------------------------------
__global__ __launch_bounds__(256) void kproj(const float* __restrict__ x,
                                             const ushortT* __restrict__ Wt,
                                             const float* __restrict__ bg,
                                             const float* __restrict__ bfv,
                                             const float* __restrict__ bh,
                                             ushortT* __restrict__ Q,
                                             ushortT* __restrict__ K,
                                             uint8_t* __restrict__ V8) {
  __shared__ ushortT Al[64 * 64];
  __shared__ ushortT Bl[64 * 64];

  const int tid = threadIdx.x;
  const int w = tid >> 6, l = tid & 63, h = l >> 4, c = l & 15;
  const int ct = blockIdx.x, rt = blockIdx.y;
  const int row0 = rt * 64;

  f4 acc[4];
#pragma unroll
  for (int j = 0; j < 4; ++j) acc[j] = (f4){0.f, 0.f, 0.f, 0.f};

  const int arow = tid >> 2, aseg = tid & 3;
  const float* xrow = x + (size_t)(row0 + arow) * 512 + aseg * 16;

  for (int kk = 0; kk < 8; ++kk) {
    const int k0 = kk * 64;
    vf4 f0 = *(const vf4*)(xrow + k0 + 0);
    vf4 f1 = *(const vf4*)(xrow + k0 + 4);
    vf4 f2 = *(const vf4*)(xrow + k0 + 8);
    vf4 f3 = *(const vf4*)(xrow + k0 + 12);
    u32x4 ch0 = { pk2(f0[0], f0[1]), pk2(f0[2], f0[3]), pk2(f1[0], f1[1]), pk2(f1[2], f1[3]) };
    u32x4 ch1 = { pk2(f2[0], f2[1]), pk2(f2[2], f2[3]), pk2(f3[0], f3[1]), pk2(f3[2], f3[3]) };
    const int sw = arow & 7;
    *(u32x4*)((char*)Al + arow * 128 + (((aseg * 2 + 0) ^ sw) * 16)) = ch0;
    *(u32x4*)((char*)Al + arow * 128 + (((aseg * 2 + 1) ^ sw) * 16)) = ch1;
#pragma unroll
    for (int j = 0; j < 2; ++j) {
      const int col = w * 16 + j * 8 + (l >> 3);
      const int c7 = l & 7;
      const ushortT* src = Wt + (size_t)(ct * 64 + col) * 512 + k0 + 8 * (c7 ^ (l >> 3));
      gl16(src, (char*)Bl + (w * 128 + j * 64) * 16);
    }
    __syncthreads();
#pragma unroll
    for (int ks = 0; ks < 2; ++ks) {
      s8v af = *(const s8v*)((char*)Al + (w * 16 + c) * 128 + (((ks * 4 + h) ^ (c & 7)) * 16));
#pragma unroll
      for (int cj = 0; cj < 4; ++cj) {
        s8v bf8 = *(const s8v*)((char*)Bl + (cj * 16 + c) * 128 + (((ks * 4 + h) ^ (c & 7)) * 16));
        acc[cj] = MFMA_BF16(af, bf8, acc[cj]);
      }
    }
    __syncthreads();
  }

  const int colbase = ct * 64;
  const float* bias = (ct == 0) ? bg : (ct == 1) ? bfv : bh;
  const int bo = (ct < 2) ? 0 : (colbase - 128);
  const int rbase = row0 + w * 16 + h * 4;
  if (ct < 2) {
    ushortT* dst = (ct == 0) ? Q : K;
#pragma unroll
    for (int cj = 0; cj < 4; ++cj) {
      const int cl = cj * 16 + c;
      const float bv = bias[cl];
#pragma unroll
      for (int r = 0; r < 4; ++r)
        dst[(size_t)(rbase + r) * 64 + cl] = (ushortT)bfr16(acc[cj][r] + bv);
    }
  } else {
    const int b = row0 >> 12;
    const int n0 = (row0 & 4095) + w * 16 + h * 4;   // multiple of 4
    const int tt = n0 >> 5, kvo = n0 & 31;
#pragma unroll
    for (int cj = 0; cj < 4; ++cj) {
      const int cl = cj * 16 + c;
      const float bv = bias[bo + cl];
      const int vcol = bo + cl;
      // bytes 0..3 = rows n0+0..n0+3 (fp8 e4m3)
      const uint32_t dd = pk4fp8(acc[cj][0] + bv, acc[cj][1] + bv,
                                 acc[cj][2] + bv, acc[cj][3] + bv);
      *(uint32_t*)(V8 + (((size_t)(b * 128 + tt) * 512 + vcol) * 32 + kvo)) = dd;
    }
  }
}

// ---------------------------------------------------------------------------
// Kernel 2: flash attention, KVBLK=64, fp8 P & V (e4m3), PV via
// mfma_f32_16x16x32_fp8_fp8 (same lane mapping as bf16 op, 1B elems).
// Structure = R5: 512 blocks x 8 waves (2 barrier domains/CU), waves 0-3
// produce P(t+1) (bf16 QK + in-register online softmax, defer-max THR=4 so
// P <= e^4 stays inside e4m3 range), all 8 waves consume P(t).
// K staged 2 ahead via gl16 into 64x64 bf16 LDS dbuf; V direct from global.
// __launch_bounds__(512,4): 2 blocks/CU requires arch VGPR <= 64.
// ---------------------------------------------------------------------------
__global__ __launch_bounds__(512, 4) void kattn(const ushortT* __restrict__ Qg,
                                                const ushortT* __restrict__ Kg,
                                                const uint8_t* __restrict__ V8,
                                                const float* __restrict__ x,
                                                const float* __restrict__ gamma,
                                                float* __restrict__ out) {
  // P fp8 frag-major: Pl[slot][kslot][(qi*64 + lane)*2 + word]  (8 KB)
  __shared__ __align__(16) uint32_t Pl[2][2][512];
  __shared__ __align__(16) ushortT Klds[2][64 * 64];      // 16KB K tiles, dbuf
  __shared__ __align__(16) float alpha_s[2][64];
  __shared__ __align__(16) int   flag_s[2][4];
  __shared__ __align__(16) float lsum_s[64];

  const int tid = threadIdx.x;
  const int w = tid >> 6, l = tid & 63, h = l >> 4, c = l & 15;
  const int bb = blockIdx.x & 7, qb = blockIdx.x >> 3;   // XCD-aware swizzle
  const size_t qrow0 = (size_t)bb * 4096 + (size_t)qb * 64;

  f4 acc[4][4];
#pragma unroll
  for (int qi = 0; qi < 4; ++qi)
#pragma unroll
    for (int vj = 0; vj < 4; ++vj) acc[qi][vj] = (f4){0.f, 0.f, 0.f, 0.f};

  const ushortT* Kb = Kg + (size_t)bb * 4096 * 64;
  const uint8_t* Vb = V8 + (size_t)bb * 512 * 4096;

  // V source (fp8): 8B per lane; wave covers 512 contiguous bytes per load.
  const uint8_t* vptr = Vb + (size_t)(w * 64 + c) * 32 + h * 8;  // +32768 B/iter
  // K staging source offset (pre-swizzled for row-XOR layout)
  const size_t koff = (size_t)(w * 16 + (l >> 3)) * 64 + 8 * ((l & 7) ^ (l >> 3));

  // Q fragments (B-operand of S^T): q = w*16 + c
  s8v qf[2];
  if (w < 4) {
#pragma unroll
    for (int ks = 0; ks < 2; ++ks)
      qf[ks] = *(const s8v*)(Qg + (qrow0 + w * 16 + c) * 64 + ks * 32 + h * 8);
  }
  float m_run = -__builtin_inff();
  float l_run = 0.0f;   // per-lane partial; combined across h at epilogue

  // softmax tail: sc[4] = S^T fragments; sc[j][r] = S[kv=j*16+h*4+r][q=w*16+c]
  auto softmax_store = [&](const f4* sc, int nb) {
    float tm = fmaxf(fmaxf(fmaxf(sc[0][0], sc[0][1]), fmaxf(sc[0][2], sc[0][3])),
                     fmaxf(fmaxf(sc[1][0], sc[1][1]), fmaxf(sc[1][2], sc[1][3])));
    tm = fmaxf(tm, fmaxf(fmaxf(fmaxf(sc[2][0], sc[2][1]), fmaxf(sc[2][2], sc[2][3])),
                         fmaxf(fmaxf(sc[3][0], sc[3][1]), fmaxf(sc[3][2], sc[3][3]))));
    // ballot-first defer-max; THR=4 keeps P <= e^4 = 54.6 << 448 (e4m3 max)
    const unsigned long long bal = __ballot(tm > m_run + 4.0f);
    float al = 1.0f;
    if (bal) {
      tm = fmaxf(tm, __shfl_xor(tm, 16));
      tm = fmaxf(tm, __shfl_xor(tm, 32));
      const float mn = fmaxf(m_run, tm);
      al = __expf(m_run - mn);   // 0 on first tile
      m_run = mn;
    }
    float ps = 0.0f;
#pragma unroll
    for (int j = 0; j < 4; ++j) {
      const float p0 = __expf(sc[j][0] - m_run), p1 = __expf(sc[j][1] - m_run);
      const float p2 = __expf(sc[j][2] - m_run), p3 = __expf(sc[j][3] - m_run);
      ps += (p0 + p1) + (p2 + p3);
      // word = fp8{p0..p3} -> kv j*16+h*4+{0..3};  consumer (qi=w) lane
      // l' = c + 16*h_c, word b:  kv = s*32 + h_c*8 + b*4 + {0..3}
      // s = j>>1, h_c = 2*(j&1) + (h>>1), b = h&1
      const uint32_t pw = pk4fp8(p0, p1, p2, p3);
      const int s = j >> 1;
      const int hc = 2 * (j & 1) + (h >> 1);
      Pl[nb][s][(w * 64 + c + 16 * hc) * 2 + (h & 1)] = pw;
    }
    l_run = l_run * al + ps;
    if (bal && h == 0) alpha_s[nb][w * 16 + c] = al;
    if (l == 0) flag_s[nb][w] = bal ? 1 : 0;
  };

  // produce from Klds[kb]: S^T for kv-tile, then softmax+store
  auto produce_lds = [&](int kb, int nb) {
    f4 sc[4];
#pragma unroll
    for (int j = 0; j < 4; ++j) sc[j] = (f4){0.f, 0.f, 0.f, 0.f};
    const char* kbp = (const char*)Klds[kb];
    __builtin_amdgcn_s_setprio(1);
#pragma unroll
    for (int j = 0; j < 4; ++j) {
#pragma unroll
      for (int ks = 0; ks < 2; ++ks) {
        s8v kf = *(const s8v*)(kbp + (size_t)(j * 16 + c) * 128 +
                               (((ks * 4 + h) ^ (c & 7)) * 16));
        sc[j] = MFMA_BF16(kf, qf[ks], sc[j]);
      }
    }
    __builtin_amdgcn_s_setprio(0);
    softmax_store(sc, nb);
  };

  // ---- prologue: produce P(0) from global K; stage K(1) -> Klds[1]
  if (w < 4) {
    f4 sc[4];
#pragma unroll
    for (int j = 0; j < 4; ++j) sc[j] = (f4){0.f, 0.f, 0.f, 0.f};
#pragma unroll
    for (int j = 0; j < 4; ++j) {
#pragma unroll
      for (int ks = 0; ks < 2; ++ks) {
        s8v kf = *(const s8v*)(Kb + (size_t)(j * 16 + c) * 64 + ks * 32 + h * 8);
        sc[j] = MFMA_BF16(kf, qf[ks], sc[j]);
      }
    }
    softmax_store(sc, 0);
    gl16(Kb + 4096 + koff, (char*)Klds[1] + w * 2048);
    gl16(Kb + 4096 + koff + 512, (char*)Klds[1] + w * 2048 + 1024);
  }
  asm volatile("s_waitcnt vmcnt(0) lgkmcnt(0)" ::: "memory");
  __builtin_amdgcn_s_barrier();

  for (int t = 0; t < 64; ++t) {
    const int cur = t & 1;
    // ---- P fragments (fp8, 8B each) + flags for tile t
    long paA[4], paB[4];
#pragma unroll
    for (int qi = 0; qi < 4; ++qi) {
      paA[qi] = *(const long*)&Pl[cur][0][(qi * 64 + l) * 2];
      paB[qi] = *(const long*)&Pl[cur][1][(qi * 64 + l) * 2];
    }
    i4v fl = *(const i4v*)&flag_s[cur][0];
    // ---- stage K(t+2) -> Klds[t&1]
    if (w < 4 && t < 62) {
      const ushortT* ks_src = Kb + (size_t)(t + 2) * 4096 + koff;
      gl16(ks_src, (char*)Klds[cur] + w * 2048);
      gl16(ks_src + 512, (char*)Klds[cur] + w * 2048 + 1024);
    }
    // ---- deferred rescale
#pragma unroll
    for (int qi = 0; qi < 4; ++qi) {
      if (fl[qi]) {
        f4 a4 = *(const f4*)&alpha_s[cur][qi * 16 + h * 4];
#pragma unroll
        for (int vj = 0; vj < 4; ++vj)
#pragma unroll
          for (int r = 0; r < 4; ++r) acc[qi][vj][r] *= a4[r];
      }
    }
    // ---- PV: 4 quarters, each {2 fp8 V-loads (8B), 8 fp8 MFMA}
#pragma unroll
    for (int vj = 0; vj < 4; ++vj) {
      const long vf0 = *(const long*)(vptr + vj * 512);
      const long vf1 = *(const long*)(vptr + 16384 + vj * 512);
      __builtin_amdgcn_s_setprio(1);
#pragma unroll
      for (int qi = 0; qi < 4; ++qi) {
        acc[qi][vj] = MFMA_FP8(paA[qi], vf0, acc[qi][vj]);
        acc[qi][vj] = MFMA_FP8(paB[qi], vf1, acc[qi][vj]);
      }
      __builtin_amdgcn_s_setprio(0);
    }
    vptr += 32768;
    // ---- produce P(t+1) from Klds[(t+1)&1]
    if (t < 63) {
      if (w < 4) produce_lds(cur ^ 1, cur ^ 1);
      asm volatile("s_waitcnt vmcnt(0) lgkmcnt(0)" ::: "memory");
      __builtin_amdgcn_s_barrier();
    }
  }

  // ---- finalize: combine per-lane l partials across h, then epilogue
  l_run += __shfl_xor(l_run, 16);
  l_run += __shfl_xor(l_run, 32);
  if (w < 4 && h == 0) lsum_s[w * 16 + c] = l_run;
  __syncthreads();
#pragma unroll
  for (int qi = 0; qi < 4; ++qi) {
    f4 l4 = *(const f4*)(&lsum_s[qi * 16 + h * 4]);
    f4 rl;
#pragma unroll
    for (int r = 0; r < 4; ++r) rl[r] = 1.0f / l4[r];
#pragma unroll
    for (int vj = 0; vj < 4; ++vj) {
      const int colg = w * 64 + vj * 16 + c;
      const float gm = gamma[colg];
#pragma unroll
      for (int r = 0; r < 4; ++r) {
        const size_t idx = (qrow0 + qi * 16 + h * 4 + r) * 512 + colg;
        out[idx] = gm * (acc[qi][vj][r] * rl[r]) + x[idx];
      }
    }
  }
}

// ---------------------------------------------------------------------------
extern "C" void kernel_launch(void* const* d_in, const int* in_sizes, int n_in,
                              void* d_out, int out_size, void* d_ws, size_t ws_size,
                              hipStream_t stream) {
  const float* x     = (const float*)d_in[0];
  const float* Wg    = (const float*)d_in[1];
  const float* bg    = (const float*)d_in[2];
  const float* Wf    = (const float*)d_in[3];
  const float* bfv   = (const float*)d_in[4];
  const float* Wh    = (const float*)d_in[5];
  const float* bh    = (const float*)d_in[6];
  const float* gamma = (const float*)d_in[7];
  float* out = (float*)d_out;
  char* ws = (char*)d_ws;

  // workspace: Q 4Mi | K 4Mi | V8 16Mi | Wt @40Mi (640KiB)
  ushortT* Q  = (ushortT*)(ws);
  ushortT* K  = (ushortT*)(ws + ((size_t)4 << 20));
  uint8_t* V8 = (uint8_t*)(ws + ((size_t)8 << 20));
  ushortT* Wt = (ushortT*)(ws + ((size_t)40 << 20));

  kprep<<<dim3(640), dim3(64), 0, stream>>>(Wg, Wf, Wh, Wt);
  kproj<<<dim3(10, 512), dim3(256), 0, stream>>>(x, Wt, bg, bfv, bh, Q, K, V8);
  kattn<<<dim3(512), dim3(512), 0, stream>>>(Q, K, V8, x, gamma, out);
}

// Round 9
// 246.001 us; speedup vs baseline: 1.3967x; 1.0240x over previous
//
#include <hip/hip_runtime.h>
#include <stdint.h>

// ---------- types ----------
using s8v  = __attribute__((ext_vector_type(8))) short;    // 8 bf16 (A/B frag)
using f4   = __attribute__((ext_vector_type(4))) float;    // C/D frag
using u32x4 = __attribute__((ext_vector_type(4))) uint32_t;
using u32x2 = __attribute__((ext_vector_type(2))) uint32_t;
using vf4  = __attribute__((ext_vector_type(4))) float;
using i4v  = __attribute__((ext_vector_type(4))) int;

typedef unsigned short ushortT;

#define LOG2E 1.4426950408889634f

// bf16 round-to-nearest-even
static __device__ __forceinline__ uint32_t bfr16(float f) {
  union { float f; uint32_t u; } v; v.f = f;
  return (v.u + 0x7FFFu + ((v.u >> 16) & 1u)) >> 16;
}
static __device__ __forceinline__ uint32_t pk2(float lo, float hi) {
  return (bfr16(hi) << 16) | (bfr16(lo) & 0xFFFFu);
}
// pack 4 f32 -> 4 fp8 e4m3 bytes (saturating RNE)
static __device__ __forceinline__ uint32_t pk4fp8(float a, float b, float cc, float d) {
  int w = __builtin_amdgcn_cvt_pk_fp8_f32(a, b, 0, false);    // bytes 0,1
  w = __builtin_amdgcn_cvt_pk_fp8_f32(cc, d, w, true);        // bytes 2,3
  return (uint32_t)w;
}
// async global->LDS, 16B per lane
static __device__ __forceinline__ void gl16(const void* g, void* l) {
  __builtin_amdgcn_global_load_lds((const __attribute__((address_space(1))) uint32_t*)g,
                                   (__attribute__((address_space(3))) uint32_t*)l, 16, 0, 0);
}

#define MFMA_BF16(A, B, C) __builtin_amdgcn_mfma_f32_16x16x32_bf16((A), (B), (C), 0, 0, 0)
#define MFMA_FP8(A, B, C)  __builtin_amdgcn_mfma_f32_16x16x32_fp8_fp8((A), (B), (C), 0, 0, 0)

// ---------------------------------------------------------------------------
// Kernel 0: weights -> bf16, transposed: Wt[640][512]
// ---------------------------------------------------------------------------
__global__ __launch_bounds__(64) void kprep(const float* __restrict__ Wg,
                                            const float* __restrict__ Wf,
                                            const float* __restrict__ Wh,
                                            ushortT* __restrict__ Wt) {
  const int cIdx = blockIdx.x;     // 0..639
  const int t = threadIdx.x;       // 64
  const float* src; int co, ldc;
  if (cIdx < 64)       { src = Wg; co = cIdx;       ldc = 64;  }
  else if (cIdx < 128) { src = Wf; co = cIdx - 64;  ldc = 64;  }
  else                 { src = Wh; co = cIdx - 128; ldc = 512; }
#pragma unroll
  for (int kk = 0; kk < 8; ++kk) {
    int k = kk * 64 + t;
    Wt[(size_t)cIdx * 512 + k] = (ushortT)bfr16(src[(size_t)k * ldc + co]);
  }
}

// ---------------------------------------------------------------------------
// Kernel 1: projection GEMM, 128x128 tile (m97 geometry).
// grid (5, 256), 256 threads = 2x2 waves, each wave 64x64 out (4x4 frags),
// BK=64, 8 K-steps.  A (x, fp32) reg-converted to bf16 -> swizzled LDS;
// B (Wt) gl16-staged (source pre-swizzled, LDS linear).
// Output routing: global col g = ct*128 + wc*64 + n*16 + c:
//   g<64 -> Q (bf16, pre-scaled by log2(e) for exp2-domain softmax)
//   g<128 -> K (bf16)
//   else -> V8 fp8 e4m3 TILED: V8[b][kvtile=128][col=512][kv=32]
// ---------------------------------------------------------------------------
__global__ __launch_bounds__(256) void kproj(const float* __restrict__ x,
                                             const ushortT* __restrict__ Wt,
                                             const float* __restrict__ bg,
                                             const float* __restrict__ bfv,
                                             const float* __restrict__ bh,
                                             ushortT* __restrict__ Q,
                                             ushortT* __restrict__ K,
                                             uint8_t* __restrict__ V8) {
  __shared__ ushortT Al[128 * 64];   // 16KB [row][k], chunk16 ^= row&7
  __shared__ ushortT Bl[128 * 64];   // 16KB [col][k], chunk16 ^= col&7

  const int tid = threadIdx.x;
  const int w = tid >> 6, l = tid & 63, h = l >> 4, c = l & 15;
  const int wr = w >> 1, wc = w & 1;           // 2x2 wave grid
  const int ct = blockIdx.x, rt = blockIdx.y;
  const int row0 = rt * 128;

  f4 acc[4][4];
#pragma unroll
  for (int m = 0; m < 4; ++m)
#pragma unroll
    for (int n = 0; n < 4; ++n) acc[m][n] = (f4){0.f, 0.f, 0.f, 0.f};

  const int arow = tid >> 1, ahalf = tid & 1;  // 128 rows x 2 half-k
  const float* xrow = x + (size_t)(row0 + arow) * 512 + ahalf * 32;
  const int asw = arow & 7;

  for (int kk = 0; kk < 8; ++kk) {
    const int k0 = kk * 64;
    // ---- stage A: 32 fp32 -> 32 bf16, 4 swizzled b128 writes
    vf4 f[8];
#pragma unroll
    for (int i = 0; i < 8; ++i) f[i] = *(const vf4*)(xrow + k0 + i * 4);
#pragma unroll
    for (int j = 0; j < 4; ++j) {
      u32x4 ch = { pk2(f[2*j][0], f[2*j][1]),   pk2(f[2*j][2], f[2*j][3]),
                   pk2(f[2*j+1][0], f[2*j+1][1]), pk2(f[2*j+1][2], f[2*j+1][3]) };
      *(u32x4*)((char*)Al + arow * 128 + (((ahalf * 4 + j) ^ asw) * 16)) = ch;
    }
    // ---- stage B: 4 gl16 per wave (source pre-swizzled, dest linear)
#pragma unroll
    for (int i = 0; i < 4; ++i) {
      const int col = w * 32 + i * 8 + (l >> 3);
      const ushortT* src = Wt + (size_t)(ct * 128 + col) * 512 + k0 +
                           8 * ((l & 7) ^ (l >> 3));
      gl16(src, (char*)Bl + (w * 4 + i) * 1024);
    }
    __syncthreads();
    // ---- MFMA: wave (wr,wc) owns rows wr*64.., cols wc*64..
#pragma unroll
    for (int ks = 0; ks < 2; ++ks) {
      s8v a[4], b[4];
#pragma unroll
      for (int m = 0; m < 4; ++m)
        a[m] = *(const s8v*)((char*)Al + (size_t)(wr * 64 + m * 16 + c) * 128 +
                             (((ks * 4 + h) ^ (c & 7)) * 16));
#pragma unroll
      for (int n = 0; n < 4; ++n)
        b[n] = *(const s8v*)((char*)Bl + (size_t)(wc * 64 + n * 16 + c) * 128 +
                             (((ks * 4 + h) ^ (c & 7)) * 16));
#pragma unroll
      for (int m = 0; m < 4; ++m)
#pragma unroll
        for (int n = 0; n < 4; ++n)
          acc[m][n] = MFMA_BF16(a[m], b[n], acc[m][n]);
    }
    __syncthreads();
  }

  // ---- epilogue: route by global column
  if (ct == 0) {
    // wc==0 -> Q (scaled by log2e), wc==1 -> K
    ushortT* dst = (wc == 0) ? Q : K;
    const float* bias = (wc == 0) ? bg : bfv;
    const float scl = (wc == 0) ? LOG2E : 1.0f;
#pragma unroll
    for (int n = 0; n < 4; ++n) {
      const int col = n * 16 + c;
      const float bv = bias[col];
#pragma unroll
      for (int m = 0; m < 4; ++m) {
        const int grow = row0 + wr * 64 + m * 16 + h * 4;
#pragma unroll
        for (int r = 0; r < 4; ++r)
          dst[(size_t)(grow + r) * 64 + col] = (ushortT)bfr16((acc[m][n][r] + bv) * scl);
      }
    }
  } else {
    const int b = row0 >> 12;
#pragma unroll
    for (int n = 0; n < 4; ++n) {
      const int vcol = ct * 128 + wc * 64 + n * 16 + c - 128;
      const float bv = bh[vcol];
#pragma unroll
      for (int m = 0; m < 4; ++m) {
        const int n0 = (row0 & 4095) + wr * 64 + m * 16 + h * 4;  // mult of 4
        const int tt = n0 >> 5, kvo = n0 & 31;
        const uint32_t dd = pk4fp8(acc[m][n][0] + bv, acc[m][n][1] + bv,
                                   acc[m][n][2] + bv, acc[m][n][3] + bv);
        *(uint32_t*)(V8 + (((size_t)(b * 128 + tt) * 512 + vcol) * 32 + kvo)) = dd;
      }
    }
  }
}

// ---------------------------------------------------------------------------
// Kernel 2: flash attention, KVBLK=64, fp8 P & V (e4m3), exp2-domain softmax
// (Q pre-scaled by log2e in kproj; v_exp_f32 is natively 2^x).
// Structure = R8: 512 blocks x 8 waves, waves 0-3 produce P(t+1), all 8
// consume P(t); K staged 2 ahead via gl16; V direct from global (L2).
// __launch_bounds__(512,4): 2 blocks/CU requires arch VGPR <= 64.
// ---------------------------------------------------------------------------
__global__ __launch_bounds__(512, 4) void kattn(const ushortT* __restrict__ Qg,
                                                const ushortT* __restrict__ Kg,
                                                const uint8_t* __restrict__ V8,
                                                const float* __restrict__ x,
                                                const float* __restrict__ gamma,
                                                float* __restrict__ out) {
  // P fp8 frag-major: Pl[slot][kslot][(qi*64 + lane)*2 + word]  (8 KB)
  __shared__ __align__(16) uint32_t Pl[2][2][512];
  __shared__ __align__(16) ushortT Klds[2][64 * 64];      // 16KB K tiles, dbuf
  __shared__ __align__(16) float alpha_s[2][64];
  __shared__ __align__(16) int   flag_s[2][4];
  __shared__ __align__(16) float lsum_s[64];

  const int tid = threadIdx.x;
  const int w = tid >> 6, l = tid & 63, h = l >> 4, c = l & 15;
  const int bb = blockIdx.x & 7, qb = blockIdx.x >> 3;   // XCD-aware swizzle
  const size_t qrow0 = (size_t)bb * 4096 + (size_t)qb * 64;

  f4 acc[4][4];
#pragma unroll
  for (int qi = 0; qi < 4; ++qi)
#pragma unroll
    for (int vj = 0; vj < 4; ++vj) acc[qi][vj] = (f4){0.f, 0.f, 0.f, 0.f};

  const ushortT* Kb = Kg + (size_t)bb * 4096 * 64;
  const uint8_t* Vb = V8 + (size_t)bb * 512 * 4096;

  // V source (fp8): 8B per lane; wave covers 512 contiguous bytes per load.
  const uint8_t* vptr = Vb + (size_t)(w * 64 + c) * 32 + h * 8;  // +32768 B/iter
  // K staging source offset (pre-swizzled for row-XOR layout)
  const size_t koff = (size_t)(w * 16 + (l >> 3)) * 64 + 8 * ((l & 7) ^ (l >> 3));

  // Q fragments (B-operand of S^T): q = w*16 + c   (pre-scaled by log2e)
  s8v qf[2];
  if (w < 4) {
#pragma unroll
    for (int ks = 0; ks < 2; ++ks)
      qf[ks] = *(const s8v*)(Qg + (qrow0 + w * 16 + c) * 64 + ks * 32 + h * 8);
  }
  float m_run = -__builtin_inff();   // log2 domain
  float l_run = 0.0f;   // per-lane partial; combined across h at epilogue

  // softmax tail (log2 domain): sc[j][r] = S2[kv=j*16+h*4+r][q=w*16+c]
  auto softmax_store = [&](const f4* sc, int nb) {
    float tm = fmaxf(fmaxf(fmaxf(sc[0][0], sc[0][1]), fmaxf(sc[0][2], sc[0][3])),
                     fmaxf(fmaxf(sc[1][0], sc[1][1]), fmaxf(sc[1][2], sc[1][3])));
    tm = fmaxf(tm, fmaxf(fmaxf(fmaxf(sc[2][0], sc[2][1]), fmaxf(sc[2][2], sc[2][3])),
                         fmaxf(fmaxf(sc[3][0], sc[3][1]), fmaxf(sc[3][2], sc[3][3]))));
    // ballot-first defer-max; THR = 4 nats = 5.77 bits -> P <= 2^5.77 = 54.6
    const unsigned long long bal = __ballot(tm > m_run + 5.77f);
    float al = 1.0f;
    if (bal) {
      tm = fmaxf(tm, __shfl_xor(tm, 16));
      tm = fmaxf(tm, __shfl_xor(tm, 32));
      const float mn = fmaxf(m_run, tm);
      al = exp2f(m_run - mn);   // 0 on first tile
      m_run = mn;
    }
    float ps = 0.0f;
#pragma unroll
    for (int j = 0; j < 4; ++j) {
      const float p0 = exp2f(sc[j][0] - m_run), p1 = exp2f(sc[j][1] - m_run);
      const float p2 = exp2f(sc[j][2] - m_run), p3 = exp2f(sc[j][3] - m_run);
      ps += (p0 + p1) + (p2 + p3);
      // word = fp8{p0..p3} -> kv j*16+h*4+{0..3}; consumer lane/word mapping:
      // s = j>>1, h_c = 2*(j&1) + (h>>1), b = h&1
      const uint32_t pw = pk4fp8(p0, p1, p2, p3);
      const int s = j >> 1;
      const int hc = 2 * (j & 1) + (h >> 1);
      Pl[nb][s][(w * 64 + c + 16 * hc) * 2 + (h & 1)] = pw;
    }
    l_run = l_run * al + ps;
    if (bal && h == 0) alpha_s[nb][w * 16 + c] = al;
    if (l == 0) flag_s[nb][w] = bal ? 1 : 0;
  };

  // produce from Klds[kb]: S^T for kv-tile, then softmax+store
  auto produce_lds = [&](int kb, int nb) {
    f4 sc[4];
#pragma unroll
    for (int j = 0; j < 4; ++j) sc[j] = (f4){0.f, 0.f, 0.f, 0.f};
    const char* kbp = (const char*)Klds[kb];
    __builtin_amdgcn_s_setprio(1);
#pragma unroll
    for (int j = 0; j < 4; ++j) {
#pragma unroll
      for (int ks = 0; ks < 2; ++ks) {
        s8v kf = *(const s8v*)(kbp + (size_t)(j * 16 + c) * 128 +
                               (((ks * 4 + h) ^ (c & 7)) * 16));
        sc[j] = MFMA_BF16(kf, qf[ks], sc[j]);
      }
    }
    __builtin_amdgcn_s_setprio(0);
    softmax_store(sc, nb);
  };

  // ---- prologue: produce P(0) from global K; stage K(1) -> Klds[1]
  if (w < 4) {
    f4 sc[4];
#pragma unroll
    for (int j = 0; j < 4; ++j) sc[j] = (f4){0.f, 0.f, 0.f, 0.f};
#pragma unroll
    for (int j = 0; j < 4; ++j) {
#pragma unroll
      for (int ks = 0; ks < 2; ++ks) {
        s8v kf = *(const s8v*)(Kb + (size_t)(j * 16 + c) * 64 + ks * 32 + h * 8);
        sc[j] = MFMA_BF16(kf, qf[ks], sc[j]);
      }
    }
    softmax_store(sc, 0);
    gl16(Kb + 4096 + koff, (char*)Klds[1] + w * 2048);
    gl16(Kb + 4096 + koff + 512, (char*)Klds[1] + w * 2048 + 1024);
  }
  asm volatile("s_waitcnt vmcnt(0) lgkmcnt(0)" ::: "memory");
  __builtin_amdgcn_s_barrier();

  for (int t = 0; t < 64; ++t) {
    const int cur = t & 1;
    // ---- P fragments (fp8, 8B each) + flags for tile t
    long paA[4], paB[4];
#pragma unroll
    for (int qi = 0; qi < 4; ++qi) {
      paA[qi] = *(const long*)&Pl[cur][0][(qi * 64 + l) * 2];
      paB[qi] = *(const long*)&Pl[cur][1][(qi * 64 + l) * 2];
    }
    i4v fl = *(const i4v*)&flag_s[cur][0];
    // ---- stage K(t+2) -> Klds[t&1]
    if (w < 4 && t < 62) {
      const ushortT* ks_src = Kb + (size_t)(t + 2) * 4096 + koff;
      gl16(ks_src, (char*)Klds[cur] + w * 2048);
      gl16(ks_src + 512, (char*)Klds[cur] + w * 2048 + 1024);
    }
    // ---- deferred rescale
#pragma unroll
    for (int qi = 0; qi < 4; ++qi) {
      if (fl[qi]) {
        f4 a4 = *(const f4*)&alpha_s[cur][qi * 16 + h * 4];
#pragma unroll
        for (int vj = 0; vj < 4; ++vj)
#pragma unroll
          for (int r = 0; r < 4; ++r) acc[qi][vj][r] *= a4[r];
      }
    }
    // ---- PV: 4 quarters, each {2 fp8 V-loads (8B), 8 fp8 MFMA}
#pragma unroll
    for (int vj = 0; vj < 4; ++vj) {
      const long vf0 = *(const long*)(vptr + vj * 512);
      const long vf1 = *(const long*)(vptr + 16384 + vj * 512);
      __builtin_amdgcn_s_setprio(1);
#pragma unroll
      for (int qi = 0; qi < 4; ++qi) {
        acc[qi][vj] = MFMA_FP8(paA[qi], vf0, acc[qi][vj]);
        acc[qi][vj] = MFMA_FP8(paB[qi], vf1, acc[qi][vj]);
      }
      __builtin_amdgcn_s_setprio(0);
    }
    vptr += 32768;
    // ---- produce P(t+1) from Klds[(t+1)&1]
    if (t < 63) {
      if (w < 4) produce_lds(cur ^ 1, cur ^ 1);
      asm volatile("s_waitcnt vmcnt(0) lgkmcnt(0)" ::: "memory");
      __builtin_amdgcn_s_barrier();
    }
  }

  // ---- finalize: combine per-lane l partials across h, then epilogue
  l_run += __shfl_xor(l_run, 16);
  l_run += __shfl_xor(l_run, 32);
  if (w < 4 && h == 0) lsum_s[w * 16 + c] = l_run;
  __syncthreads();
#pragma unroll
  for (int qi = 0; qi < 4; ++qi) {
    f4 l4 = *(const f4*)(&lsum_s[qi * 16 + h * 4]);
    f4 rl;
#pragma unroll
    for (int r = 0; r < 4; ++r) rl[r] = 1.0f / l4[r];
#pragma unroll
    for (int vj = 0; vj < 4; ++vj) {
      const int colg = w * 64 + vj * 16 + c;
      const float gm = gamma[colg];
#pragma unroll
      for (int r = 0; r < 4; ++r) {
        const size_t idx = (qrow0 + qi * 16 + h * 4 + r) * 512 + colg;
        out[idx] = gm * (acc[qi][vj][r] * rl[r]) + x[idx];
      }
    }
  }
}

// ---------------------------------------------------------------------------
extern "C" void kernel_launch(void* const* d_in, const int* in_sizes, int n_in,
                              void* d_out, int out_size, void* d_ws, size_t ws_size,
                              hipStream_t stream) {
  const float* x     = (const float*)d_in[0];
  const float* Wg    = (const float*)d_in[1];
  const float* bg    = (const float*)d_in[2];
  const float* Wf    = (const float*)d_in[3];
  const float* bfv   = (const float*)d_in[4];
  const float* Wh    = (const float*)d_in[5];
  const float* bh    = (const float*)d_in[6];
  const float* gamma = (const float*)d_in[7];
  float* out = (float*)d_out;
  char* ws = (char*)d_ws;

  // workspace: Q 4Mi | K 4Mi | V8 16Mi | Wt @40Mi (640KiB)
  ushortT* Q  = (ushortT*)(ws);
  ushortT* K  = (ushortT*)(ws + ((size_t)4 << 20));
  uint8_t* V8 = (uint8_t*)(ws + ((size_t)8 << 20));
  ushortT* Wt = (ushortT*)(ws + ((size_t)40 << 20));

  kprep<<<dim3(640), dim3(64), 0, stream>>>(Wg, Wf, Wh, Wt);
  kproj<<<dim3(5, 256), dim3(256), 0, stream>>>(x, Wt, bg, bfv, bh, Q, K, V8);
  kattn<<<dim3(512), dim3(512), 0, stream>>>(Q, K, V8, x, gamma, out);
}

// Round 10
// 235.770 us; speedup vs baseline: 1.4573x; 1.0434x over previous
//
#include <hip/hip_runtime.h>
#include <stdint.h>

// ---------- types ----------
using s8v  = __attribute__((ext_vector_type(8))) short;    // 8 bf16 (A/B frag)
using f4   = __attribute__((ext_vector_type(4))) float;    // C/D frag
using u32x4 = __attribute__((ext_vector_type(4))) uint32_t;
using u32x2 = __attribute__((ext_vector_type(2))) uint32_t;
using vf4  = __attribute__((ext_vector_type(4))) float;
using i4v  = __attribute__((ext_vector_type(4))) int;

typedef unsigned short ushortT;

#define LOG2E 1.4426950408889634f

// bf16 round-to-nearest-even
static __device__ __forceinline__ uint32_t bfr16(float f) {
  union { float f; uint32_t u; } v; v.f = f;
  return (v.u + 0x7FFFu + ((v.u >> 16) & 1u)) >> 16;
}
static __device__ __forceinline__ uint32_t pk2(float lo, float hi) {
  return (bfr16(hi) << 16) | (bfr16(lo) & 0xFFFFu);
}
// pack 4 f32 -> 4 fp8 e4m3 bytes (saturating RNE)
static __device__ __forceinline__ uint32_t pk4fp8(float a, float b, float cc, float d) {
  int w = __builtin_amdgcn_cvt_pk_fp8_f32(a, b, 0, false);    // bytes 0,1
  w = __builtin_amdgcn_cvt_pk_fp8_f32(cc, d, w, true);        // bytes 2,3
  return (uint32_t)w;
}
// native 2^x (single v_exp_f32 — exp2f() is a slow libm call, R9 lesson)
static __device__ __forceinline__ float ex2(float x) {
#if __has_builtin(__builtin_amdgcn_exp2f)
  return __builtin_amdgcn_exp2f(x);
#else
  float r; asm("v_exp_f32 %0, %1" : "=v"(r) : "v"(x)); return r;
#endif
}
// async global->LDS, 16B per lane
static __device__ __forceinline__ void gl16(const void* g, void* l) {
  __builtin_amdgcn_global_load_lds((const __attribute__((address_space(1))) uint32_t*)g,
                                   (__attribute__((address_space(3))) uint32_t*)l, 16, 0, 0);
}

#define MFMA_BF16(A, B, C) __builtin_amdgcn_mfma_f32_16x16x32_bf16((A), (B), (C), 0, 0, 0)
#define MFMA_FP8(A, B, C)  __builtin_amdgcn_mfma_f32_16x16x32_fp8_fp8((A), (B), (C), 0, 0, 0)

// ---------------------------------------------------------------------------
// Kernel 0: weights -> bf16, transposed: Wt[640][512]
// ---------------------------------------------------------------------------
__global__ __launch_bounds__(64) void kprep(const float* __restrict__ Wg,
                                            const float* __restrict__ Wf,
                                            const float* __restrict__ Wh,
                                            ushortT* __restrict__ Wt) {
  const int cIdx = blockIdx.x;     // 0..639
  const int t = threadIdx.x;       // 64
  const float* src; int co, ldc;
  if (cIdx < 64)       { src = Wg; co = cIdx;       ldc = 64;  }
  else if (cIdx < 128) { src = Wf; co = cIdx - 64;  ldc = 64;  }
  else                 { src = Wh; co = cIdx - 128; ldc = 512; }
#pragma unroll
  for (int kk = 0; kk < 8; ++kk) {
    int k = kk * 64 + t;
    Wt[(size_t)cIdx * 512 + k] = (ushortT)bfr16(src[(size_t)k * ldc + co]);
  }
}

// ---------------------------------------------------------------------------
// Kernel 1: projection GEMM, 128x128 tile (m97 geometry).  Unchanged from R9.
// ---------------------------------------------------------------------------
__global__ __launch_bounds__(256) void kproj(const float* __restrict__ x,
                                             const ushortT* __restrict__ Wt,
                                             const float* __restrict__ bg,
                                             const float* __restrict__ bfv,
                                             const float* __restrict__ bh,
                                             ushortT* __restrict__ Q,
                                             ushortT* __restrict__ K,
                                             uint8_t* __restrict__ V8) {
  __shared__ ushortT Al[128 * 64];   // 16KB [row][k], chunk16 ^= row&7
  __shared__ ushortT Bl[128 * 64];   // 16KB [col][k], chunk16 ^= col&7

  const int tid = threadIdx.x;
  const int w = tid >> 6, l = tid & 63, h = l >> 4, c = l & 15;
  const int wr = w >> 1, wc = w & 1;           // 2x2 wave grid
  const int ct = blockIdx.x, rt = blockIdx.y;
  const int row0 = rt * 128;

  f4 acc[4][4];
#pragma unroll
  for (int m = 0; m < 4; ++m)
#pragma unroll
    for (int n = 0; n < 4; ++n) acc[m][n] = (f4){0.f, 0.f, 0.f, 0.f};

  const int arow = tid >> 1, ahalf = tid & 1;  // 128 rows x 2 half-k
  const float* xrow = x + (size_t)(row0 + arow) * 512 + ahalf * 32;
  const int asw = arow & 7;

  for (int kk = 0; kk < 8; ++kk) {
    const int k0 = kk * 64;
    // ---- stage A: 32 fp32 -> 32 bf16, 4 swizzled b128 writes
    vf4 f[8];
#pragma unroll
    for (int i = 0; i < 8; ++i) f[i] = *(const vf4*)(xrow + k0 + i * 4);
#pragma unroll
    for (int j = 0; j < 4; ++j) {
      u32x4 ch = { pk2(f[2*j][0], f[2*j][1]),   pk2(f[2*j][2], f[2*j][3]),
                   pk2(f[2*j+1][0], f[2*j+1][1]), pk2(f[2*j+1][2], f[2*j+1][3]) };
      *(u32x4*)((char*)Al + arow * 128 + (((ahalf * 4 + j) ^ asw) * 16)) = ch;
    }
    // ---- stage B: 4 gl16 per wave (source pre-swizzled, dest linear)
#pragma unroll
    for (int i = 0; i < 4; ++i) {
      const int col = w * 32 + i * 8 + (l >> 3);
      const ushortT* src = Wt + (size_t)(ct * 128 + col) * 512 + k0 +
                           8 * ((l & 7) ^ (l >> 3));
      gl16(src, (char*)Bl + (w * 4 + i) * 1024);
    }
    __syncthreads();
    // ---- MFMA: wave (wr,wc) owns rows wr*64.., cols wc*64..
#pragma unroll
    for (int ks = 0; ks < 2; ++ks) {
      s8v a[4], b[4];
#pragma unroll
      for (int m = 0; m < 4; ++m)
        a[m] = *(const s8v*)((char*)Al + (size_t)(wr * 64 + m * 16 + c) * 128 +
                             (((ks * 4 + h) ^ (c & 7)) * 16));
#pragma unroll
      for (int n = 0; n < 4; ++n)
        b[n] = *(const s8v*)((char*)Bl + (size_t)(wc * 64 + n * 16 + c) * 128 +
                             (((ks * 4 + h) ^ (c & 7)) * 16));
#pragma unroll
      for (int m = 0; m < 4; ++m)
#pragma unroll
        for (int n = 0; n < 4; ++n)
          acc[m][n] = MFMA_BF16(a[m], b[n], acc[m][n]);
    }
    __syncthreads();
  }

  // ---- epilogue: route by global column
  if (ct == 0) {
    // wc==0 -> Q (scaled by log2e), wc==1 -> K
    ushortT* dst = (wc == 0) ? Q : K;
    const float* bias = (wc == 0) ? bg : bfv;
    const float scl = (wc == 0) ? LOG2E : 1.0f;
#pragma unroll
    for (int n = 0; n < 4; ++n) {
      const int col = n * 16 + c;
      const float bv = bias[col];
#pragma unroll
      for (int m = 0; m < 4; ++m) {
        const int grow = row0 + wr * 64 + m * 16 + h * 4;
#pragma unroll
        for (int r = 0; r < 4; ++r)
          dst[(size_t)(grow + r) * 64 + col] = (ushortT)bfr16((acc[m][n][r] + bv) * scl);
      }
    }
  } else {
    const int b = row0 >> 12;
#pragma unroll
    for (int n = 0; n < 4; ++n) {
      const int vcol = ct * 128 + wc * 64 + n * 16 + c - 128;
      const float bv = bh[vcol];
#pragma unroll
      for (int m = 0; m < 4; ++m) {
        const int n0 = (row0 & 4095) + wr * 64 + m * 16 + h * 4;  // mult of 4
        const int tt = n0 >> 5, kvo = n0 & 31;
        const uint32_t dd = pk4fp8(acc[m][n][0] + bv, acc[m][n][1] + bv,
                                   acc[m][n][2] + bv, acc[m][n][3] + bv);
        *(uint32_t*)(V8 + (((size_t)(b * 128 + tt) * 512 + vcol) * 32 + kvo)) = dd;
      }
    }
  }
}

// ---------------------------------------------------------------------------
// Kernel 2: flash attention, KVBLK=64, fp8 P & V, exp2-domain softmax with
// NATIVE v_exp_f32.  K-tile gl16 staging moved to V-waves (w>=4): the S-wave
// produce chain gates the barrier, so its issue slots + vmcnt drain must stay
// clean; V-waves idle post-PV and absorb staging latency for free.
// __launch_bounds__(512,4): 2 blocks/CU requires arch VGPR <= 64.
// ---------------------------------------------------------------------------
__global__ __launch_bounds__(512, 4) void kattn(const ushortT* __restrict__ Qg,
                                                const ushortT* __restrict__ Kg,
                                                const uint8_t* __restrict__ V8,
                                                const float* __restrict__ x,
                                                const float* __restrict__ gamma,
                                                float* __restrict__ out) {
  // P fp8 frag-major: Pl[slot][kslot][(qi*64 + lane)*2 + word]  (8 KB)
  __shared__ __align__(16) uint32_t Pl[2][2][512];
  __shared__ __align__(16) ushortT Klds[2][64 * 64];      // 16KB K tiles, dbuf
  __shared__ __align__(16) float alpha_s[2][64];
  __shared__ __align__(16) int   flag_s[2][4];
  __shared__ __align__(16) float lsum_s[64];

  const int tid = threadIdx.x;
  const int w = tid >> 6, l = tid & 63, h = l >> 4, c = l & 15;
  const int bb = blockIdx.x & 7, qb = blockIdx.x >> 3;   // XCD-aware swizzle
  const size_t qrow0 = (size_t)bb * 4096 + (size_t)qb * 64;

  f4 acc[4][4];
#pragma unroll
  for (int qi = 0; qi < 4; ++qi)
#pragma unroll
    for (int vj = 0; vj < 4; ++vj) acc[qi][vj] = (f4){0.f, 0.f, 0.f, 0.f};

  const ushortT* Kb = Kg + (size_t)bb * 4096 * 64;
  const uint8_t* Vb = V8 + (size_t)bb * 512 * 4096;

  // V source (fp8): 8B per lane; wave covers 512 contiguous bytes per load.
  const uint8_t* vptr = Vb + (size_t)(w * 64 + c) * 32 + h * 8;  // +32768 B/iter
  // K staging source offset for stager waves w>=4 (pre-swizzled; w&3 quarter)
  const size_t koff = (size_t)((w & 3) * 16 + (l >> 3)) * 64 +
                      8 * ((l & 7) ^ (l >> 3));

  // Q fragments (B-operand of S^T): q = w*16 + c   (pre-scaled by log2e)
  s8v qf[2];
  if (w < 4) {
#pragma unroll
    for (int ks = 0; ks < 2; ++ks)
      qf[ks] = *(const s8v*)(Qg + (qrow0 + w * 16 + c) * 64 + ks * 32 + h * 8);
  }
  float m_run = -__builtin_inff();   // log2 domain
  float l_run = 0.0f;   // per-lane partial; combined across h at epilogue

  // softmax tail (log2 domain): sc[j][r] = S2[kv=j*16+h*4+r][q=w*16+c]
  auto softmax_store = [&](const f4* sc, int nb) {
    float tm = fmaxf(fmaxf(fmaxf(sc[0][0], sc[0][1]), fmaxf(sc[0][2], sc[0][3])),
                     fmaxf(fmaxf(sc[1][0], sc[1][1]), fmaxf(sc[1][2], sc[1][3])));
    tm = fmaxf(tm, fmaxf(fmaxf(fmaxf(sc[2][0], sc[2][1]), fmaxf(sc[2][2], sc[2][3])),
                         fmaxf(fmaxf(sc[3][0], sc[3][1]), fmaxf(sc[3][2], sc[3][3]))));
    // ballot-first defer-max; THR = 4 nats = 5.77 bits -> P <= 2^5.77 = 54.6
    const unsigned long long bal = __ballot(tm > m_run + 5.77f);
    float al = 1.0f;
    if (bal) {
      tm = fmaxf(tm, __shfl_xor(tm, 16));
      tm = fmaxf(tm, __shfl_xor(tm, 32));
      const float mn = fmaxf(m_run, tm);
      al = ex2(m_run - mn);   // 0 on first tile
      m_run = mn;
    }
    float ps = 0.0f;
#pragma unroll
    for (int j = 0; j < 4; ++j) {
      const float p0 = ex2(sc[j][0] - m_run), p1 = ex2(sc[j][1] - m_run);
      const float p2 = ex2(sc[j][2] - m_run), p3 = ex2(sc[j][3] - m_run);
      ps += (p0 + p1) + (p2 + p3);
      // word = fp8{p0..p3} -> kv j*16+h*4+{0..3}; consumer lane/word mapping:
      // s = j>>1, h_c = 2*(j&1) + (h>>1), b = h&1
      const uint32_t pw = pk4fp8(p0, p1, p2, p3);
      const int s = j >> 1;
      const int hc = 2 * (j & 1) + (h >> 1);
      Pl[nb][s][(w * 64 + c + 16 * hc) * 2 + (h & 1)] = pw;
    }
    l_run = l_run * al + ps;
    if (bal && h == 0) alpha_s[nb][w * 16 + c] = al;
    if (l == 0) flag_s[nb][w] = bal ? 1 : 0;
  };

  // produce from Klds[kb]: S^T for kv-tile, then softmax+store
  auto produce_lds = [&](int kb, int nb) {
    f4 sc[4];
#pragma unroll
    for (int j = 0; j < 4; ++j) sc[j] = (f4){0.f, 0.f, 0.f, 0.f};
    const char* kbp = (const char*)Klds[kb];
    __builtin_amdgcn_s_setprio(1);
#pragma unroll
    for (int j = 0; j < 4; ++j) {
#pragma unroll
      for (int ks = 0; ks < 2; ++ks) {
        s8v kf = *(const s8v*)(kbp + (size_t)(j * 16 + c) * 128 +
                               (((ks * 4 + h) ^ (c & 7)) * 16));
        sc[j] = MFMA_BF16(kf, qf[ks], sc[j]);
      }
    }
    __builtin_amdgcn_s_setprio(0);
    softmax_store(sc, nb);
  };

  // ---- prologue: S-waves produce P(0) from global K; V-waves stage K(1)
  if (w < 4) {
    f4 sc[4];
#pragma unroll
    for (int j = 0; j < 4; ++j) sc[j] = (f4){0.f, 0.f, 0.f, 0.f};
#pragma unroll
    for (int j = 0; j < 4; ++j) {
#pragma unroll
      for (int ks = 0; ks < 2; ++ks) {
        s8v kf = *(const s8v*)(Kb + (size_t)(j * 16 + c) * 64 + ks * 32 + h * 8);
        sc[j] = MFMA_BF16(kf, qf[ks], sc[j]);
      }
    }
    softmax_store(sc, 0);
  } else {
    gl16(Kb + 4096 + koff, (char*)Klds[1] + (w & 3) * 2048);
    gl16(Kb + 4096 + koff + 512, (char*)Klds[1] + (w & 3) * 2048 + 1024);
  }
  asm volatile("s_waitcnt vmcnt(0) lgkmcnt(0)" ::: "memory");
  __builtin_amdgcn_s_barrier();

  for (int t = 0; t < 64; ++t) {
    const int cur = t & 1;
    // ---- P fragments (fp8, 8B each) + flags for tile t
    long paA[4], paB[4];
#pragma unroll
    for (int qi = 0; qi < 4; ++qi) {
      paA[qi] = *(const long*)&Pl[cur][0][(qi * 64 + l) * 2];
      paB[qi] = *(const long*)&Pl[cur][1][(qi * 64 + l) * 2];
    }
    i4v fl = *(const i4v*)&flag_s[cur][0];
    // ---- stagers (V-waves): K(t+2) -> Klds[t&1]
    if (w >= 4 && t < 62) {
      const ushortT* ks_src = Kb + (size_t)(t + 2) * 4096 + koff;
      gl16(ks_src, (char*)Klds[cur] + (w & 3) * 2048);
      gl16(ks_src + 512, (char*)Klds[cur] + (w & 3) * 2048 + 1024);
    }
    // ---- deferred rescale
#pragma unroll
    for (int qi = 0; qi < 4; ++qi) {
      if (fl[qi]) {
        f4 a4 = *(const f4*)&alpha_s[cur][qi * 16 + h * 4];
#pragma unroll
        for (int vj = 0; vj < 4; ++vj)
#pragma unroll
          for (int r = 0; r < 4; ++r) acc[qi][vj][r] *= a4[r];
      }
    }
    // ---- PV: 4 quarters, each {2 fp8 V-loads (8B), 8 fp8 MFMA}
#pragma unroll
    for (int vj = 0; vj < 4; ++vj) {
      const long vf0 = *(const long*)(vptr + vj * 512);
      const long vf1 = *(const long*)(vptr + 16384 + vj * 512);
      __builtin_amdgcn_s_setprio(1);
#pragma unroll
      for (int qi = 0; qi < 4; ++qi) {
        acc[qi][vj] = MFMA_FP8(paA[qi], vf0, acc[qi][vj]);
        acc[qi][vj] = MFMA_FP8(paB[qi], vf1, acc[qi][vj]);
      }
      __builtin_amdgcn_s_setprio(0);
    }
    vptr += 32768;
    // ---- S-waves: produce P(t+1) from Klds[(t+1)&1]
    if (t < 63) {
      if (w < 4) produce_lds(cur ^ 1, cur ^ 1);
      asm volatile("s_waitcnt vmcnt(0) lgkmcnt(0)" ::: "memory");
      __builtin_amdgcn_s_barrier();
    }
  }

  // ---- finalize: combine per-lane l partials across h, then epilogue
  l_run += __shfl_xor(l_run, 16);
  l_run += __shfl_xor(l_run, 32);
  if (w < 4 && h == 0) lsum_s[w * 16 + c] = l_run;
  __syncthreads();
#pragma unroll
  for (int qi = 0; qi < 4; ++qi) {
    f4 l4 = *(const f4*)(&lsum_s[qi * 16 + h * 4]);
    f4 rl;
#pragma unroll
    for (int r = 0; r < 4; ++r) rl[r] = 1.0f / l4[r];
#pragma unroll
    for (int vj = 0; vj < 4; ++vj) {
      const int colg = w * 64 + vj * 16 + c;
      const float gm = gamma[colg];
#pragma unroll
      for (int r = 0; r < 4; ++r) {
        const size_t idx = (qrow0 + qi * 16 + h * 4 + r) * 512 + colg;
        out[idx] = gm * (acc[qi][vj][r] * rl[r]) + x[idx];
      }
    }
  }
}

// ---------------------------------------------------------------------------
extern "C" void kernel_launch(void* const* d_in, const int* in_sizes, int n_in,
                              void* d_out, int out_size, void* d_ws, size_t ws_size,
                              hipStream_t stream) {
  const float* x     = (const float*)d_in[0];
  const float* Wg    = (const float*)d_in[1];
  const float* bg    = (const float*)d_in[2];
  const float* Wf    = (const float*)d_in[3];
  const float* bfv   = (const float*)d_in[4];
  const float* Wh    = (const float*)d_in[5];
  const float* bh    = (const float*)d_in[6];
  const float* gamma = (const float*)d_in[7];
  float* out = (float*)d_out;
  char* ws = (char*)d_ws;

  // workspace: Q 4Mi | K 4Mi | V8 16Mi | Wt @40Mi (640KiB)
  ushortT* Q  = (ushortT*)(ws);
  ushortT* K  = (ushortT*)(ws + ((size_t)4 << 20));
  uint8_t* V8 = (uint8_t*)(ws + ((size_t)8 << 20));
  ushortT* Wt = (ushortT*)(ws + ((size_t)40 << 20));

  kprep<<<dim3(640), dim3(64), 0, stream>>>(Wg, Wf, Wh, Wt);
  kproj<<<dim3(5, 256), dim3(256), 0, stream>>>(x, Wt, bg, bfv, bh, Q, K, V8);
  kattn<<<dim3(512), dim3(512), 0, stream>>>(Q, K, V8, x, gamma, out);
}